// Round 1
// baseline (479.934 us; speedup 1.0000x reference)
//
#include <hip/hip_runtime.h>

#define DD 256
#define HH 256
#define WW 256
#define RMAX 6

__global__ __launch_bounds__(256) void splat_kernel(
    const float* __restrict__ center,    // [N,3]
    const float* __restrict__ cov_inv,   // [N,9]
    const float* __restrict__ dens_r,    // [N]
    const float* __restrict__ dens_i,    // [N]
    const float* __restrict__ radius,    // [N]
    const float* __restrict__ half_shape,// [3]
    float* __restrict__ vol_r,
    float* __restrict__ vol_i,
    int N)
{
    int g = blockIdx.x;
    if (g >= N) return;

    // Per-Gaussian parameters (broadcast loads; L1/L2 absorb redundancy)
    float cx = center[3*g+0], cy = center[3*g+1], cz = center[3*g+2];
    float r  = radius[g];
    float c00 = cov_inv[9*g+0], c01 = cov_inv[9*g+1], c02 = cov_inv[9*g+2];
    float c10 = cov_inv[9*g+3], c11 = cov_inv[9*g+4], c12 = cov_inv[9*g+5];
    float c20 = cov_inv[9*g+6], c21 = cov_inv[9*g+7], c22 = cov_inv[9*g+8];
    float dr = dens_r[g], di = dens_i[g];
    float ihx = 1.0f / half_shape[0], ihy = 1.0f / half_shape[1], ihz = 1.0f / half_shape[2];

    int bx = (int)floorf(cx), by = (int)floorf(cy), bz = (int)floorf(cz);

    // bbox ∩ window ∩ grid per axis. centers ∈ [R, D-R] so c-r >= 0 → int cast == floor.
    int xlo = max(max((int)floorf(cx - r), bx - RMAX), 0);
    int xhi = min(min((int)ceilf (cx + r), bx + RMAX), DD - 1);
    int ylo = max(max((int)floorf(cy - r), by - RMAX), 0);
    int yhi = min(min((int)ceilf (cy + r), by + RMAX), HH - 1);
    int zlo = max(max((int)floorf(cz - r), bz - RMAX), 0);
    int zhi = min(min((int)ceilf (cz + r), bz + RMAX), WW - 1);

    int nx = xhi - xlo + 1;
    int ny = yhi - ylo + 1;
    int nz = zhi - zlo + 1;
    if (nx <= 0 || ny <= 0 || nz <= 0) return;
    int total = nx * ny * nz;

    for (int k = threadIdx.x; k < total; k += 256) {
        int iz = k % nz;
        int t  = k / nz;
        int iy = t % ny;
        int ix = t / ny;
        int vx = xlo + ix, vy = ylo + iy, vz = zlo + iz;

        float dx = ((float)vx - cx) * ihx;
        float dy = ((float)vy - cy) * ihy;
        float dz = ((float)vz - cz) * ihz;

        // full (symmetric) quadratic form, matches reference einsum
        float md = dx * (c00*dx + c01*dy + c02*dz)
                 + dy * (c10*dx + c11*dy + c12*dz)
                 + dz * (c20*dx + c21*dy + c22*dz);

        if (md <= 9.0f) {
            float w = __expf(-0.5f * md);
            int flat = (vx * HH + vy) * WW + vz;
            atomicAdd(&vol_r[flat], w * dr);
            atomicAdd(&vol_i[flat], w * di);
        }
    }
}

extern "C" void kernel_launch(void* const* d_in, const int* in_sizes, int n_in,
                              void* d_out, int out_size, void* d_ws, size_t ws_size,
                              hipStream_t stream) {
    const float* center     = (const float*)d_in[0];
    const float* cov_inv    = (const float*)d_in[1];
    const float* dens_r     = (const float*)d_in[2];
    const float* dens_i     = (const float*)d_in[3];
    const float* radius     = (const float*)d_in[4];
    const float* half_shape = (const float*)d_in[5];
    int N = in_sizes[0] / 3;

    float* vol_r = (float*)d_out;
    float* vol_i = vol_r + (size_t)DD * HH * WW;

    // zero the 2 volumes (harness poisons d_out with 0xAA before every call)
    hipMemsetAsync(d_out, 0, (size_t)out_size * sizeof(float), stream);

    splat_kernel<<<N, 256, 0, stream>>>(center, cov_inv, dens_r, dens_i,
                                        radius, half_shape, vol_r, vol_i, N);
}

// Round 3
// 221.195 us; speedup vs baseline: 2.1697x; 2.1697x over previous
//
#include <hip/hip_runtime.h>

#define DD 256
#define HH 256
#define WW 256
#define RMAX 6

// tile = 4 x 4 x 16 voxels, one wave (64 threads) per tile, 4 z-voxels/thread
#define NTX 64
#define NTY 64
#define NTZ 16
#define NTILES (NTX * NTY * NTZ)   // 65536
#define CAP 32                     // per-tile gaussian list capacity
#define OVF_CAP 8192               // overflow pair capacity (never expected to hit)

// ---------------- binning / packing ----------------
__global__ __launch_bounds__(256) void fill_kernel(
    const float* __restrict__ center, const float* __restrict__ cov_inv,
    const float* __restrict__ dens_r, const float* __restrict__ dens_i,
    const float* __restrict__ radius,
    int* __restrict__ tile_cnt, int* __restrict__ tile_list,
    int* __restrict__ ovf_cnt, int* __restrict__ ovf_list,
    float* __restrict__ packed, int N)
{
    int i = blockIdx.x * 256 + threadIdx.x;
    if (i >= N) return;
    float cx = center[3*i+0], cy = center[3*i+1], cz = center[3*i+2];
    float r  = radius[i];
    float c00=cov_inv[9*i+0], c01=cov_inv[9*i+1], c02=cov_inv[9*i+2];
    float c10=cov_inv[9*i+3], c11=cov_inv[9*i+4], c12=cov_inv[9*i+5];
    float c20=cov_inv[9*i+6], c21=cov_inv[9*i+7], c22=cov_inv[9*i+8];

    float* P = packed + 12*i;
    P[0]=cx; P[1]=cy; P[2]=cz;
    P[3]=c00; P[4]=c11; P[5]=c22;              // diagonal
    P[6]=c01+c10; P[7]=c02+c20; P[8]=c12+c21;  // symmetric cross terms
    P[9]=dens_r[i]; P[10]=dens_i[i]; P[11]=r;

    int bx=(int)floorf(cx), by=(int)floorf(cy), bz=(int)floorf(cz);
    int xlo = max(max((int)floorf(cx - r), bx - RMAX), 0);
    int xhi = min(min((int)ceilf (cx + r), bx + RMAX), DD - 1);
    int ylo = max(max((int)floorf(cy - r), by - RMAX), 0);
    int yhi = min(min((int)ceilf (cy + r), by + RMAX), HH - 1);
    int zlo = max(max((int)floorf(cz - r), bz - RMAX), 0);
    int zhi = min(min((int)ceilf (cz + r), bz + RMAX), WW - 1);
    if (xlo > xhi || ylo > yhi || zlo > zhi) return;

    for (int tx = xlo >> 2; tx <= (xhi >> 2); ++tx)
        for (int ty = ylo >> 2; ty <= (yhi >> 2); ++ty)
            for (int tz = zlo >> 4; tz <= (zhi >> 4); ++tz) {
                int tile = (tx << 10) | (ty << 4) | tz;
                int pos = atomicAdd(&tile_cnt[tile], 1);
                if (pos < CAP) {
                    tile_list[tile * CAP + pos] = i;
                } else {
                    int o = atomicAdd(ovf_cnt, 1);
                    if (o < OVF_CAP) { ovf_list[2*o] = tile; ovf_list[2*o+1] = i; }
                }
            }
}

// ---------------- gather: one wave per tile, write-once ----------------
__global__ __launch_bounds__(64) void gather_kernel(
    const int* __restrict__ tile_cnt, const int* __restrict__ tile_list,
    const float* __restrict__ packed, const float* __restrict__ half_shape,
    float* __restrict__ vol_r, float* __restrict__ vol_i)
{
    int tile = blockIdx.x;
    int tz = tile & 15, ty = (tile >> 4) & 63, tx = tile >> 10;
    int t = threadIdx.x;
    int dx = t >> 4, dy = (t >> 2) & 3, dzq = t & 3;
    int vx = tx*4 + dx, vy = ty*4 + dy, vz0 = tz*16 + dzq*4;
    float vxf = (float)vx, vyf = (float)vy;
    float ihx = 1.0f/half_shape[0], ihy = 1.0f/half_shape[1], ihz = 1.0f/half_shape[2];

    float accr[4] = {0.f,0.f,0.f,0.f};
    float acci[4] = {0.f,0.f,0.f,0.f};

    int n = min(tile_cnt[tile], CAP);
    for (int j = 0; j < n; ++j) {
        int g = __builtin_amdgcn_readfirstlane(tile_list[tile * CAP + j]);
        const float* P = packed + 12*g;
        float cx=P[0], cy=P[1], cz=P[2];
        float s00=P[3], s11=P[4], s22=P[5];
        float s01=P[6], s02=P[7], s12=P[8];
        float dr=P[9], di=P[10], r=P[11];

        int bxi=(int)floorf(cx), byi=(int)floorf(cy), bzi=(int)floorf(cz);
        int xlo = max(max((int)floorf(cx - r), bxi - RMAX), 0);
        int xhi = min(min((int)ceilf (cx + r), bxi + RMAX), DD - 1);
        int ylo = max(max((int)floorf(cy - r), byi - RMAX), 0);
        int yhi = min(min((int)ceilf (cy + r), byi + RMAX), HH - 1);
        int zlo = max(max((int)floorf(cz - r), bzi - RMAX), 0);
        int zhi = min(min((int)ceilf (cz + r), bzi + RMAX), WW - 1);

        bool okxy = (vx >= xlo) && (vx <= xhi) && (vy >= ylo) && (vy <= yhi);
        float fx = (vxf - cx) * ihx;
        float fy = (vyf - cy) * ihy;
        float axy = s00*fx*fx + s01*fx*fy + s11*fy*fy;
        float bxy = s02*fx + s12*fy;

        #pragma unroll
        for (int k = 0; k < 4; ++k) {
            int vz = vz0 + k;
            float fz = ((float)vz - cz) * ihz;
            float md = axy + fz*(bxy + s22*fz);
            bool ok = okxy && (vz >= zlo) && (vz <= zhi) && (md <= 9.0f);
            if (ok) {
                float w = __expf(-0.5f * md);
                accr[k] += w * dr;
                acci[k] += w * di;
            }
        }
    }

    size_t flat = ((size_t)vx * HH + vy) * WW + vz0;   // vz0 % 4 == 0 -> 16B aligned
    *(float4*)(vol_r + flat) = make_float4(accr[0], accr[1], accr[2], accr[3]);
    *(float4*)(vol_i + flat) = make_float4(acci[0], acci[1], acci[2], acci[3]);
}

// ---------------- overflow safety net (expected empty) ----------------
__global__ __launch_bounds__(256) void ovf_kernel(
    const int* __restrict__ ovf_cnt, const int* __restrict__ ovf_list,
    const float* __restrict__ packed, const float* __restrict__ half_shape,
    float* __restrict__ vol_r, float* __restrict__ vol_i)
{
    int total = min(ovf_cnt[0], OVF_CAP);
    if (total == 0) return;
    float ihx = 1.0f/half_shape[0], ihy = 1.0f/half_shape[1], ihz = 1.0f/half_shape[2];
    long work = (long)total * 64;
    for (long idx = (long)blockIdx.x * blockDim.x + threadIdx.x; idx < work;
         idx += (long)gridDim.x * blockDim.x) {
        int p = (int)(idx >> 6), lane = (int)(idx & 63);
        int tile = ovf_list[2*p], g = ovf_list[2*p+1];
        int tz = tile & 15, ty = (tile >> 4) & 63, tx = tile >> 10;
        int dx = lane >> 4, dy = (lane >> 2) & 3, dzq = lane & 3;
        int vx = tx*4 + dx, vy = ty*4 + dy, vz0 = tz*16 + dzq*4;

        const float* P = packed + 12*g;
        float cx=P[0], cy=P[1], cz=P[2];
        float s00=P[3], s11=P[4], s22=P[5];
        float s01=P[6], s02=P[7], s12=P[8];
        float dr=P[9], di=P[10], r=P[11];

        int bxi=(int)floorf(cx), byi=(int)floorf(cy), bzi=(int)floorf(cz);
        int xlo = max(max((int)floorf(cx - r), bxi - RMAX), 0);
        int xhi = min(min((int)ceilf (cx + r), bxi + RMAX), DD - 1);
        int ylo = max(max((int)floorf(cy - r), byi - RMAX), 0);
        int yhi = min(min((int)ceilf (cy + r), byi + RMAX), HH - 1);
        int zlo = max(max((int)floorf(cz - r), bzi - RMAX), 0);
        int zhi = min(min((int)ceilf (cz + r), bzi + RMAX), WW - 1);

        if ((vx < xlo) || (vx > xhi) || (vy < ylo) || (vy > yhi)) continue;
        float fx = ((float)vx - cx) * ihx;
        float fy = ((float)vy - cy) * ihy;
        float axy = s00*fx*fx + s01*fx*fy + s11*fy*fy;
        float bxy = s02*fx + s12*fy;
        for (int k = 0; k < 4; ++k) {
            int vz = vz0 + k;
            float fz = ((float)vz - cz) * ihz;
            float md = axy + fz*(bxy + s22*fz);
            if ((vz >= zlo) && (vz <= zhi) && (md <= 9.0f)) {
                float w = __expf(-0.5f * md);
                size_t flat = ((size_t)vx * HH + vy) * WW + vz;
                atomicAdd(&vol_r[flat], w * dr);
                atomicAdd(&vol_i[flat], w * di);
            }
        }
    }
}

// ---------------- fallback scatter (only if ws too small) ----------------
__global__ __launch_bounds__(256) void splat_kernel(
    const float* __restrict__ center, const float* __restrict__ cov_inv,
    const float* __restrict__ dens_r, const float* __restrict__ dens_i,
    const float* __restrict__ radius, const float* __restrict__ half_shape,
    float* __restrict__ vol_r, float* __restrict__ vol_i, int N)
{
    int g = blockIdx.x;
    if (g >= N) return;
    float cx = center[3*g+0], cy = center[3*g+1], cz = center[3*g+2];
    float r  = radius[g];
    float c00 = cov_inv[9*g+0], c01 = cov_inv[9*g+1], c02 = cov_inv[9*g+2];
    float c10 = cov_inv[9*g+3], c11 = cov_inv[9*g+4], c12 = cov_inv[9*g+5];
    float c20 = cov_inv[9*g+6], c21 = cov_inv[9*g+7], c22 = cov_inv[9*g+8];
    float dr = dens_r[g], di = dens_i[g];
    float ihx = 1.0f/half_shape[0], ihy = 1.0f/half_shape[1], ihz = 1.0f/half_shape[2];
    int bx = (int)floorf(cx), by = (int)floorf(cy), bz = (int)floorf(cz);
    int xlo = max(max((int)floorf(cx - r), bx - RMAX), 0);
    int xhi = min(min((int)ceilf (cx + r), bx + RMAX), DD - 1);
    int ylo = max(max((int)floorf(cy - r), by - RMAX), 0);
    int yhi = min(min((int)ceilf (cy + r), by + RMAX), HH - 1);
    int zlo = max(max((int)floorf(cz - r), bz - RMAX), 0);
    int zhi = min(min((int)ceilf (cz + r), bz + RMAX), WW - 1);
    int nx = xhi-xlo+1, ny = yhi-ylo+1, nz = zhi-zlo+1;
    if (nx <= 0 || ny <= 0 || nz <= 0) return;
    int total = nx*ny*nz;
    for (int k = threadIdx.x; k < total; k += 256) {
        int iz = k % nz, tq = k / nz, iy = tq % ny, ix = tq / ny;
        int vx = xlo+ix, vy = ylo+iy, vz = zlo+iz;
        float dxn = ((float)vx - cx) * ihx;
        float dyn = ((float)vy - cy) * ihy;
        float dzn = ((float)vz - cz) * ihz;
        float md = dxn*(c00*dxn + c01*dyn + c02*dzn)
                 + dyn*(c10*dxn + c11*dyn + c12*dzn)
                 + dzn*(c20*dxn + c21*dyn + c22*dzn);
        if (md <= 9.0f) {
            float w = __expf(-0.5f*md);
            int flat = (vx*HH + vy)*WW + vz;
            atomicAdd(&vol_r[flat], w*dr);
            atomicAdd(&vol_i[flat], w*di);
        }
    }
}

extern "C" void kernel_launch(void* const* d_in, const int* in_sizes, int n_in,
                              void* d_out, int out_size, void* d_ws, size_t ws_size,
                              hipStream_t stream) {
    const float* center     = (const float*)d_in[0];
    const float* cov_inv    = (const float*)d_in[1];
    const float* dens_r     = (const float*)d_in[2];
    const float* dens_i     = (const float*)d_in[3];
    const float* radius     = (const float*)d_in[4];
    const float* half_shape = (const float*)d_in[5];
    int N = in_sizes[0] / 3;

    float* vol_r = (float*)d_out;
    float* vol_i = vol_r + (size_t)DD * HH * WW;

    // ws layout
    size_t need = ((size_t)NTILES + 4 + 2*OVF_CAP + (size_t)NTILES*CAP) * sizeof(int)
                  + (size_t)N * 12 * sizeof(float);
    if (ws_size < need) {
        // fallback: proven scatter path
        (void)hipMemsetAsync(d_out, 0, (size_t)out_size * sizeof(float), stream);
        splat_kernel<<<N, 256, 0, stream>>>(center, cov_inv, dens_r, dens_i,
                                            radius, half_shape, vol_r, vol_i, N);
        return;
    }

    int* tile_cnt  = (int*)d_ws;                     // NTILES
    int* ovf_cnt   = tile_cnt + NTILES;              // 4 (one used)
    int* ovf_list  = ovf_cnt + 4;                    // 2*OVF_CAP
    int* tile_list = ovf_list + 2*OVF_CAP;           // NTILES*CAP
    float* packed  = (float*)(tile_list + (size_t)NTILES * CAP);  // N*12

    (void)hipMemsetAsync(tile_cnt, 0, ((size_t)NTILES + 4) * sizeof(int), stream);
    fill_kernel<<<(N + 255)/256, 256, 0, stream>>>(center, cov_inv, dens_r, dens_i,
                                                   radius, tile_cnt, tile_list,
                                                   ovf_cnt, ovf_list, packed, N);
    gather_kernel<<<NTILES, 64, 0, stream>>>(tile_cnt, tile_list, packed, half_shape,
                                             vol_r, vol_i);
    ovf_kernel<<<64, 256, 0, stream>>>(ovf_cnt, ovf_list, packed, half_shape,
                                       vol_r, vol_i);
}

// Round 5
// 219.750 us; speedup vs baseline: 2.1840x; 1.0066x over previous
//
#include <hip/hip_runtime.h>

#define DD 256
#define HH 256
#define WW 256
#define RMAX 6

// tiles: 64 x 64 x 16 tiles of 4 x 4 x 16 voxels. tile id = (tx<<10)|(ty<<4)|tz
#define NTILES 65536
#define CAP 24        // inline records per tile (Poisson lambda ~3-4; ovf net covers excess)
#define RECSZ 16      // floats per record (64 B)
#define OVF_CAP 8192

// ---------------- binning: write full records inline ----------------
__global__ __launch_bounds__(256) void fill_kernel(
    const float* __restrict__ center, const float* __restrict__ cov_inv,
    const float* __restrict__ dens_r, const float* __restrict__ dens_i,
    const float* __restrict__ radius, const float* __restrict__ half_shape,
    int* __restrict__ tile_cnt, float* __restrict__ tile_recs,
    int* __restrict__ ovf_cnt, int* __restrict__ ovf_list, int N)
{
    int i = blockIdx.x * 256 + threadIdx.x;
    if (i >= N) return;
    float cx = center[3*i+0], cy = center[3*i+1], cz = center[3*i+2];
    float r  = radius[i];
    // cov_inv is exactly symmetric by construction (A A^T + I scaled)
    float c00=cov_inv[9*i+0], c01=cov_inv[9*i+1], c02=cov_inv[9*i+2];
    float c11=cov_inv[9*i+4], c12=cov_inv[9*i+5], c22=cov_inv[9*i+8];

    // ellipsoid extents: max |d_axis| on {Md<=9} is sqrt(9*(M^-1)_ii) (normalized),
    // scaled by half_shape to voxels. Voxels beyond extent have Md>9 strictly ->
    // exact pruning of the reference bbox (mask would zero them anyway).
    float d00 = c11*c22 - c12*c12;
    float d11 = c00*c22 - c02*c02;
    float d22 = c00*c11 - c01*c01;
    float det = c00*d00 - c01*(c01*c22 - c02*c12) + c02*(c01*c12 - c02*c11);
    float k9  = 9.0f / det;          // det > 0 (SPD)
    float hx = half_shape[0], hy = half_shape[1], hz = half_shape[2];
    float ex = hx * sqrtf(d00 * k9) * 1.0001f + 0.01f;
    float ey = hy * sqrtf(d11 * k9) * 1.0001f + 0.01f;
    float ez = hz * sqrtf(d22 * k9) * 1.0001f + 0.01f;
    float rx = fminf(r, ex), ry = fminf(r, ey), rz = fminf(r, ez);

    int bx=(int)floorf(cx), by=(int)floorf(cy), bz=(int)floorf(cz);
    int xlo = max(max((int)floorf(cx - rx), bx - RMAX), 0);
    int xhi = min(min((int)ceilf (cx + rx), bx + RMAX), DD - 1);
    int ylo = max(max((int)floorf(cy - ry), by - RMAX), 0);
    int yhi = min(min((int)ceilf (cy + ry), by + RMAX), HH - 1);
    int zlo = max(max((int)floorf(cz - rz), bz - RMAX), 0);
    int zhi = min(min((int)ceilf (cz + rz), bz + RMAX), WW - 1);
    if (xlo > xhi || ylo > yhi || zlo > zhi) return;

    unsigned lo = (unsigned)xlo | ((unsigned)ylo << 8) | ((unsigned)zlo << 16);
    unsigned hi = (unsigned)xhi | ((unsigned)yhi << 8) | ((unsigned)zhi << 16);
    float4 r0 = make_float4(cx, cy, cz, c00);
    float4 r1 = make_float4(c11, c22, c01 + c01, c02 + c02);
    float4 r2 = make_float4(c12 + c12, dens_r[i], dens_i[i], __uint_as_float(lo));
    float4 r3 = make_float4(__uint_as_float(hi), 0.f, 0.f, 0.f);

    for (int tx = xlo >> 2; tx <= (xhi >> 2); ++tx)
        for (int ty = ylo >> 2; ty <= (yhi >> 2); ++ty)
            for (int tz = zlo >> 4; tz <= (zhi >> 4); ++tz) {
                int tile = (tx << 10) | (ty << 4) | tz;
                int pos = atomicAdd(&tile_cnt[tile], 1);
                if (pos < CAP) {
                    float4* R = (float4*)(tile_recs + ((size_t)tile * CAP + pos) * RECSZ);
                    R[0] = r0; R[1] = r1; R[2] = r2; R[3] = r3;
                } else {
                    int o = atomicAdd(ovf_cnt, 1);
                    if (o < OVF_CAP) { ovf_list[2*o] = tile; ovf_list[2*o+1] = i; }
                }
            }
}

// ---------------- gather: 4 tiles/block, LDS-staged lists, write-once ----------------
__global__ __launch_bounds__(256) void gather_kernel(
    const int* __restrict__ tile_cnt, const float* __restrict__ tile_recs,
    const float* __restrict__ half_shape,
    float* __restrict__ vol_r, float* __restrict__ vol_i)
{
    __shared__ float4 lds[4 * CAP * 4];   // 6 KB
    int w = threadIdx.x >> 6, lane = threadIdx.x & 63;
    int tile = (blockIdx.x << 2) | w;
    int tz = tile & 15, ty = (tile >> 4) & 63, tx = tile >> 10;
    int dxl = lane >> 4, dyl = (lane >> 2) & 3, dzq = lane & 3;
    int vx = tx*4 + dxl, vy = ty*4 + dyl, vz0 = tz*16 + dzq*4;
    float vxf = (float)vx, vyf = (float)vy, vz0f = (float)vz0;
    float ihx = 1.0f/half_shape[0], ihy = 1.0f/half_shape[1], ihz = 1.0f/half_shape[2];

    int n = min(tile_cnt[tile], CAP);
    float4* wl = lds + w * (CAP * 4);
    const float4* src = (const float4*)(tile_recs + (size_t)tile * CAP * RECSZ);
    for (int idx = lane; idx < n * 4; idx += 64) wl[idx] = src[idx];
    __syncthreads();

    float ar0=0.f, ar1=0.f, ar2=0.f, ar3=0.f;
    float ai0=0.f, ai1=0.f, ai2=0.f, ai3=0.f;

    for (int j = 0; j < n; ++j) {
        float4 r0 = wl[j*4+0];
        float4 r1 = wl[j*4+1];
        float4 r2 = wl[j*4+2];
        float4 r3 = wl[j*4+3];
        float cx=r0.x, cy=r0.y, cz=r0.z, s00=r0.w;
        float s11=r1.x, s22=r1.y, s01=r1.z, s02=r1.w;
        float s12=r2.x, dr=r2.y, di=r2.z;
        unsigned lo = __float_as_uint(r2.w), hi = __float_as_uint(r3.x);
        int xlo = lo & 255, ylo = (lo >> 8) & 255, zlo = (lo >> 16) & 255;
        int xhi = hi & 255, yhi = (hi >> 8) & 255, zhi = (hi >> 16) & 255;

        bool okxy = (vx >= xlo) & (vx <= xhi) & (vy >= ylo) & (vy <= yhi);
        float fx = (vxf - cx) * ihx;
        float fy = (vyf - cy) * ihy;
        float axy = fx*fx*s00 + fx*fy*s01 + fy*fy*s11;
        float bxy = fx*s02 + fy*s12;
        float nczihz = -cz * ihz;

        float fz0 = fmaf(vz0f, ihz, nczihz);
        float fz1 = fz0 + ihz;
        float fz2 = fz1 + ihz;
        float fz3 = fz2 + ihz;
        float md0 = fmaf(fz0, fmaf(s22, fz0, bxy), axy);
        float md1 = fmaf(fz1, fmaf(s22, fz1, bxy), axy);
        float md2 = fmaf(fz2, fmaf(s22, fz2, bxy), axy);
        float md3 = fmaf(fz3, fmaf(s22, fz3, bxy), axy);

        bool ok0 = okxy & (vz0   >= zlo) & (vz0   <= zhi) & (md0 <= 9.0f);
        bool ok1 = okxy & (vz0+1 >= zlo) & (vz0+1 <= zhi) & (md1 <= 9.0f);
        bool ok2 = okxy & (vz0+2 >= zlo) & (vz0+2 <= zhi) & (md2 <= 9.0f);
        bool ok3 = okxy & (vz0+3 >= zlo) & (vz0+3 <= zhi) & (md3 <= 9.0f);

        if (__any(ok0 | ok1 | ok2 | ok3)) {
            float w0 = ok0 ? __expf(md0 * -0.5f) : 0.0f;
            float w1 = ok1 ? __expf(md1 * -0.5f) : 0.0f;
            float w2 = ok2 ? __expf(md2 * -0.5f) : 0.0f;
            float w3 = ok3 ? __expf(md3 * -0.5f) : 0.0f;
            ar0 = fmaf(w0, dr, ar0); ai0 = fmaf(w0, di, ai0);
            ar1 = fmaf(w1, dr, ar1); ai1 = fmaf(w1, di, ai1);
            ar2 = fmaf(w2, dr, ar2); ai2 = fmaf(w2, di, ai2);
            ar3 = fmaf(w3, dr, ar3); ai3 = fmaf(w3, di, ai3);
        }
    }

    size_t flat = ((size_t)vx * HH + vy) * WW + vz0;   // vz0 % 4 == 0 -> 16B aligned
    *(float4*)(vol_r + flat) = make_float4(ar0, ar1, ar2, ar3);
    *(float4*)(vol_i + flat) = make_float4(ai0, ai1, ai2, ai3);
}

// ---------------- overflow safety net (expected empty), reads raw inputs ----------------
__global__ __launch_bounds__(64) void ovf_kernel(
    const int* __restrict__ ovf_cnt, const int* __restrict__ ovf_list,
    const float* __restrict__ center, const float* __restrict__ cov_inv,
    const float* __restrict__ dens_r, const float* __restrict__ dens_i,
    const float* __restrict__ radius, const float* __restrict__ half_shape,
    float* __restrict__ vol_r, float* __restrict__ vol_i)
{
    int total = min(ovf_cnt[0], OVF_CAP);
    float ihx = 1.0f/half_shape[0], ihy = 1.0f/half_shape[1], ihz = 1.0f/half_shape[2];
    int lane = threadIdx.x;
    for (int p = blockIdx.x; p < total; p += gridDim.x) {
        int tile = ovf_list[2*p], g = ovf_list[2*p+1];
        int tz = tile & 15, ty = (tile >> 4) & 63, tx = tile >> 10;
        int dxl = lane >> 4, dyl = (lane >> 2) & 3, dzq = lane & 3;
        int vx = tx*4 + dxl, vy = ty*4 + dyl, vz0 = tz*16 + dzq*4;

        float cx = center[3*g+0], cy = center[3*g+1], cz = center[3*g+2];
        float r  = radius[g];
        float c00=cov_inv[9*g+0], c01=cov_inv[9*g+1], c02=cov_inv[9*g+2];
        float c10=cov_inv[9*g+3], c11=cov_inv[9*g+4], c12=cov_inv[9*g+5];
        float c20=cov_inv[9*g+6], c21=cov_inv[9*g+7], c22=cov_inv[9*g+8];
        float dr = dens_r[g], di = dens_i[g];

        int bx=(int)floorf(cx), by=(int)floorf(cy), bz=(int)floorf(cz);
        int xlo = max(max((int)floorf(cx - r), bx - RMAX), 0);
        int xhi = min(min((int)ceilf (cx + r), bx + RMAX), DD - 1);
        int ylo = max(max((int)floorf(cy - r), by - RMAX), 0);
        int yhi = min(min((int)ceilf (cy + r), by + RMAX), HH - 1);
        int zlo = max(max((int)floorf(cz - r), bz - RMAX), 0);
        int zhi = min(min((int)ceilf (cz + r), bz + RMAX), WW - 1);

        if (vx < xlo || vx > xhi || vy < ylo || vy > yhi) continue;
        float fx = ((float)vx - cx) * ihx;
        float fy = ((float)vy - cy) * ihy;
        for (int k = 0; k < 4; ++k) {
            int vz = vz0 + k;
            float fz = ((float)vz - cz) * ihz;
            float md = fx*(c00*fx + c01*fy + c02*fz)
                     + fy*(c10*fx + c11*fy + c12*fz)
                     + fz*(c20*fx + c21*fy + c22*fz);
            if (vz >= zlo && vz <= zhi && md <= 9.0f) {
                float wgt = __expf(-0.5f * md);
                size_t flat = ((size_t)vx * HH + vy) * WW + vz;
                atomicAdd(&vol_r[flat], wgt * dr);
                atomicAdd(&vol_i[flat], wgt * di);
            }
        }
    }
}

// ---------------- fallback scatter (only if ws too small) ----------------
__global__ __launch_bounds__(256) void splat_kernel(
    const float* __restrict__ center, const float* __restrict__ cov_inv,
    const float* __restrict__ dens_r, const float* __restrict__ dens_i,
    const float* __restrict__ radius, const float* __restrict__ half_shape,
    float* __restrict__ vol_r, float* __restrict__ vol_i, int N)
{
    int g = blockIdx.x;
    if (g >= N) return;
    float cx = center[3*g+0], cy = center[3*g+1], cz = center[3*g+2];
    float r  = radius[g];
    float c00 = cov_inv[9*g+0], c01 = cov_inv[9*g+1], c02 = cov_inv[9*g+2];
    float c10 = cov_inv[9*g+3], c11 = cov_inv[9*g+4], c12 = cov_inv[9*g+5];
    float c20 = cov_inv[9*g+6], c21 = cov_inv[9*g+7], c22 = cov_inv[9*g+8];
    float dr = dens_r[g], di = dens_i[g];
    float ihx = 1.0f/half_shape[0], ihy = 1.0f/half_shape[1], ihz = 1.0f/half_shape[2];
    int bx = (int)floorf(cx), by = (int)floorf(cy), bz = (int)floorf(cz);
    int xlo = max(max((int)floorf(cx - r), bx - RMAX), 0);
    int xhi = min(min((int)ceilf (cx + r), bx + RMAX), DD - 1);
    int ylo = max(max((int)floorf(cy - r), by - RMAX), 0);
    int yhi = min(min((int)ceilf (cy + r), by + RMAX), HH - 1);
    int zlo = max(max((int)floorf(cz - r), bz - RMAX), 0);
    int zhi = min(min((int)ceilf (cz + r), bz + RMAX), WW - 1);
    int nx = xhi-xlo+1, ny = yhi-ylo+1, nz = zhi-zlo+1;
    if (nx <= 0 || ny <= 0 || nz <= 0) return;
    int total = nx*ny*nz;
    for (int k = threadIdx.x; k < total; k += 256) {
        int iz = k % nz, tq = k / nz, iy = tq % ny, ix = tq / ny;
        int vx = xlo+ix, vy = ylo+iy, vz = zlo+iz;
        float dxn = ((float)vx - cx) * ihx;
        float dyn = ((float)vy - cy) * ihy;
        float dzn = ((float)vz - cz) * ihz;
        float md = dxn*(c00*dxn + c01*dyn + c02*dzn)
                 + dyn*(c10*dxn + c11*dyn + c12*dzn)
                 + dzn*(c20*dxn + c21*dyn + c22*dzn);
        if (md <= 9.0f) {
            float wgt = __expf(-0.5f*md);
            int flat = (vx*HH + vy)*WW + vz;
            atomicAdd(&vol_r[flat], wgt*dr);
            atomicAdd(&vol_i[flat], wgt*di);
        }
    }
}

extern "C" void kernel_launch(void* const* d_in, const int* in_sizes, int n_in,
                              void* d_out, int out_size, void* d_ws, size_t ws_size,
                              hipStream_t stream) {
    const float* center     = (const float*)d_in[0];
    const float* cov_inv    = (const float*)d_in[1];
    const float* dens_r     = (const float*)d_in[2];
    const float* dens_i     = (const float*)d_in[3];
    const float* radius     = (const float*)d_in[4];
    const float* half_shape = (const float*)d_in[5];
    int N = in_sizes[0] / 3;

    float* vol_r = (float*)d_out;
    float* vol_i = vol_r + (size_t)DD * HH * WW;

    // ws layout: [tile_recs | tile_cnt | ovf_cnt | ovf_list]
    size_t rec_floats = (size_t)NTILES * CAP * RECSZ;           // ~100.7 MB
    size_t need = rec_floats * sizeof(float)
                + ((size_t)NTILES + 4 + 2*OVF_CAP) * sizeof(int);
    if (ws_size < need) {
        (void)hipMemsetAsync(d_out, 0, (size_t)out_size * sizeof(float), stream);
        splat_kernel<<<N, 256, 0, stream>>>(center, cov_inv, dens_r, dens_i,
                                            radius, half_shape, vol_r, vol_i, N);
        return;
    }

    float* tile_recs = (float*)d_ws;
    int*   tile_cnt  = (int*)(tile_recs + rec_floats);   // NTILES
    int*   ovf_cnt   = tile_cnt + NTILES;                // 4
    int*   ovf_list  = ovf_cnt + 4;                      // 2*OVF_CAP

    (void)hipMemsetAsync(tile_cnt, 0, ((size_t)NTILES + 4) * sizeof(int), stream);
    fill_kernel<<<(N + 255)/256, 256, 0, stream>>>(center, cov_inv, dens_r, dens_i,
                                                   radius, half_shape,
                                                   tile_cnt, tile_recs,
                                                   ovf_cnt, ovf_list, N);
    gather_kernel<<<NTILES/4, 256, 0, stream>>>(tile_cnt, tile_recs, half_shape,
                                                vol_r, vol_i);
    ovf_kernel<<<64, 64, 0, stream>>>(ovf_cnt, ovf_list, center, cov_inv,
                                      dens_r, dens_i, radius, half_shape,
                                      vol_r, vol_i);
}

// Round 6
// 200.362 us; speedup vs baseline: 2.3953x; 1.0968x over previous
//
#include <hip/hip_runtime.h>

#define DD 256
#define HH 256
#define WW 256
#define RMAX 6

// tiles: 64 x 64 x 16 tiles of 4 x 4 x 16 voxels. tile id = (tx<<10)|(ty<<4)|tz
#define NTILES 65536
#define CAP 24        // inline records per tile (lambda ~4; ovf net covers excess)
#define RECSZ 16      // floats per record (64 B)
#define OVF_CAP 8192

// ---------------- binning: ONE WAVE PER GAUSSIAN, lanes = overlapped tiles ----------------
__global__ __launch_bounds__(256) void fill_kernel(
    const float* __restrict__ center, const float* __restrict__ cov_inv,
    const float* __restrict__ dens_r, const float* __restrict__ dens_i,
    const float* __restrict__ radius, const float* __restrict__ half_shape,
    int* __restrict__ tile_cnt, float* __restrict__ tile_recs,
    int* __restrict__ ovf_cnt, int* __restrict__ ovf_list, int N)
{
    int lane = threadIdx.x & 63;
    int i = __builtin_amdgcn_readfirstlane(blockIdx.x * 4 + (threadIdx.x >> 6));
    if (i >= N) return;

    float cx = center[3*i+0], cy = center[3*i+1], cz = center[3*i+2];
    float r  = radius[i];
    // cov_inv is exactly symmetric by construction (A A^T + I scaled)
    float c00=cov_inv[9*i+0], c01=cov_inv[9*i+1], c02=cov_inv[9*i+2];
    float c11=cov_inv[9*i+4], c12=cov_inv[9*i+5], c22=cov_inv[9*i+8];

    // ellipsoid extents: |d_axis| > sqrt(9*(M^-1)_ii) (normalized) => Md > 9 strictly,
    // so tightening the bbox to the extent is exact w.r.t. the reference mask.
    float d00 = c11*c22 - c12*c12;
    float d11 = c00*c22 - c02*c02;
    float d22 = c00*c11 - c01*c01;
    float det = c00*d00 - c01*(c01*c22 - c02*c12) + c02*(c01*c12 - c02*c11);
    float k9  = 9.0f / det;          // det > 0 (SPD)
    float hx = half_shape[0], hy = half_shape[1], hz = half_shape[2];
    float ex = hx * sqrtf(d00 * k9) * 1.0001f + 0.01f;
    float ey = hy * sqrtf(d11 * k9) * 1.0001f + 0.01f;
    float ez = hz * sqrtf(d22 * k9) * 1.0001f + 0.01f;
    float rx = fminf(r, ex), ry = fminf(r, ey), rz = fminf(r, ez);

    int bx=(int)floorf(cx), by=(int)floorf(cy), bz=(int)floorf(cz);
    int xlo = max(max((int)floorf(cx - rx), bx - RMAX), 0);
    int xhi = min(min((int)ceilf (cx + rx), bx + RMAX), DD - 1);
    int ylo = max(max((int)floorf(cy - ry), by - RMAX), 0);
    int yhi = min(min((int)ceilf (cy + ry), by + RMAX), HH - 1);
    int zlo = max(max((int)floorf(cz - rz), bz - RMAX), 0);
    int zhi = min(min((int)ceilf (cz + rz), bz + RMAX), WW - 1);
    if (xlo > xhi || ylo > yhi || zlo > zhi) return;

    int tx0 = xlo >> 2, ntx = (xhi >> 2) - tx0 + 1;
    int ty0 = ylo >> 2, nty = (yhi >> 2) - ty0 + 1;
    int tz0 = zlo >> 4, ntz = (zhi >> 4) - tz0 + 1;
    int ntiles = ntx * nty * ntz;          // <= 4*4*2 = 32 <= 64 lanes

    if (lane >= ntiles) return;

    unsigned lo = (unsigned)xlo | ((unsigned)ylo << 8) | ((unsigned)zlo << 16);
    unsigned hi = (unsigned)xhi | ((unsigned)yhi << 8) | ((unsigned)zhi << 16);
    float4 r0 = make_float4(cx, cy, cz, c00);
    float4 r1 = make_float4(c11, c22, c01 + c01, c02 + c02);
    float4 r2 = make_float4(c12 + c12, dens_r[i], dens_i[i], __uint_as_float(lo));
    float4 r3 = make_float4(__uint_as_float(hi), 0.f, 0.f, 0.f);

    int t = lane;
    int tzz = tz0 + (t % ntz); t /= ntz;
    int tyy = ty0 + (t % nty); t /= nty;
    int txx = tx0 + t;
    int tile = (txx << 10) | (tyy << 4) | tzz;

    int pos = atomicAdd(&tile_cnt[tile], 1);
    if (pos < CAP) {
        float4* R = (float4*)(tile_recs + ((size_t)tile * CAP + pos) * RECSZ);
        R[0] = r0; R[1] = r1; R[2] = r2; R[3] = r3;
    } else {
        int o = atomicAdd(ovf_cnt, 1);
        if (o < OVF_CAP) { ovf_list[2*o] = tile; ovf_list[2*o+1] = i; }
    }
}

// ---------------- gather: 4 tiles/block, per-wave LDS staging, write-once ----------------
__global__ __launch_bounds__(256) void gather_kernel(
    const int* __restrict__ tile_cnt, const float* __restrict__ tile_recs,
    const float* __restrict__ half_shape,
    float* __restrict__ vol_r, float* __restrict__ vol_i)
{
    __shared__ float4 lds[4 * CAP * 4];   // 6 KB, disjoint per wave
    int w = threadIdx.x >> 6, lane = threadIdx.x & 63;
    int tile = (blockIdx.x << 2) | w;
    int tz = tile & 15, ty = (tile >> 4) & 63, tx = tile >> 10;
    int dxl = lane >> 4, dyl = (lane >> 2) & 3, dzq = lane & 3;
    int vx = tx*4 + dxl, vy = ty*4 + dyl, vz0 = tz*16 + dzq*4;
    float vxf = (float)vx, vyf = (float)vy, vz0f = (float)vz0;
    float ihx = 1.0f/half_shape[0], ihy = 1.0f/half_shape[1], ihz = 1.0f/half_shape[2];

    int n = min(tile_cnt[tile], CAP);
    float4* wl = lds + w * (CAP * 4);
    const float4* src = (const float4*)(tile_recs + (size_t)tile * CAP * RECSZ);
    for (int idx = lane; idx < n * 4; idx += 64) wl[idx] = src[idx];
    // no __syncthreads: each wave reads only the LDS region it wrote itself

    float ar0=0.f, ar1=0.f, ar2=0.f, ar3=0.f;
    float ai0=0.f, ai1=0.f, ai2=0.f, ai3=0.f;

    for (int j = 0; j < n; ++j) {
        float4 r0 = wl[j*4+0];
        float4 r1 = wl[j*4+1];
        float4 r2 = wl[j*4+2];
        float4 r3 = wl[j*4+3];
        float cx=r0.x, cy=r0.y, cz=r0.z, s00=r0.w;
        float s11=r1.x, s22=r1.y, s01=r1.z, s02=r1.w;
        float s12=r2.x, dr=r2.y, di=r2.z;
        unsigned lo = __float_as_uint(r2.w), hi = __float_as_uint(r3.x);
        int xlo = lo & 255, ylo = (lo >> 8) & 255, zlo = (lo >> 16) & 255;
        int xhi = hi & 255, yhi = (hi >> 8) & 255, zhi = (hi >> 16) & 255;

        // unsigned-range trick: vx<xlo wraps to huge -> false
        bool okxy = ((unsigned)(vx - xlo) <= (unsigned)(xhi - xlo)) &
                    ((unsigned)(vy - ylo) <= (unsigned)(yhi - ylo));
        int iz0 = vz0 - zlo;
        unsigned zspan = (unsigned)(zhi - zlo);

        float fx = (vxf - cx) * ihx;
        float fy = (vyf - cy) * ihy;
        float axy = fx*fx*s00 + fx*fy*s01 + fy*fy*s11;
        float bxy = fx*s02 + fy*s12;
        float nczihz = -cz * ihz;

        float fz0 = fmaf(vz0f, ihz, nczihz);
        float fz1 = fz0 + ihz;
        float fz2 = fz1 + ihz;
        float fz3 = fz2 + ihz;
        float md0 = fmaf(fz0, fmaf(s22, fz0, bxy), axy);
        float md1 = fmaf(fz1, fmaf(s22, fz1, bxy), axy);
        float md2 = fmaf(fz2, fmaf(s22, fz2, bxy), axy);
        float md3 = fmaf(fz3, fmaf(s22, fz3, bxy), axy);

        bool ok0 = okxy & ((unsigned)(iz0    ) <= zspan) & (md0 <= 9.0f);
        bool ok1 = okxy & ((unsigned)(iz0 + 1) <= zspan) & (md1 <= 9.0f);
        bool ok2 = okxy & ((unsigned)(iz0 + 2) <= zspan) & (md2 <= 9.0f);
        bool ok3 = okxy & ((unsigned)(iz0 + 3) <= zspan) & (md3 <= 9.0f);

        if (__any(ok0 | ok1 | ok2 | ok3)) {
            float w0 = ok0 ? __expf(md0 * -0.5f) : 0.0f;
            float w1 = ok1 ? __expf(md1 * -0.5f) : 0.0f;
            float w2 = ok2 ? __expf(md2 * -0.5f) : 0.0f;
            float w3 = ok3 ? __expf(md3 * -0.5f) : 0.0f;
            ar0 = fmaf(w0, dr, ar0); ai0 = fmaf(w0, di, ai0);
            ar1 = fmaf(w1, dr, ar1); ai1 = fmaf(w1, di, ai1);
            ar2 = fmaf(w2, dr, ar2); ai2 = fmaf(w2, di, ai2);
            ar3 = fmaf(w3, dr, ar3); ai3 = fmaf(w3, di, ai3);
        }
    }

    size_t flat = ((size_t)vx * HH + vy) * WW + vz0;   // vz0 % 4 == 0 -> 16B aligned
    *(float4*)(vol_r + flat) = make_float4(ar0, ar1, ar2, ar3);
    *(float4*)(vol_i + flat) = make_float4(ai0, ai1, ai2, ai3);
}

// ---------------- overflow safety net (expected empty), reads raw inputs ----------------
__global__ __launch_bounds__(64) void ovf_kernel(
    const int* __restrict__ ovf_cnt, const int* __restrict__ ovf_list,
    const float* __restrict__ center, const float* __restrict__ cov_inv,
    const float* __restrict__ dens_r, const float* __restrict__ dens_i,
    const float* __restrict__ radius, const float* __restrict__ half_shape,
    float* __restrict__ vol_r, float* __restrict__ vol_i)
{
    int total = min(ovf_cnt[0], OVF_CAP);
    float ihx = 1.0f/half_shape[0], ihy = 1.0f/half_shape[1], ihz = 1.0f/half_shape[2];
    int lane = threadIdx.x;
    for (int p = blockIdx.x; p < total; p += gridDim.x) {
        int tile = ovf_list[2*p], g = ovf_list[2*p+1];
        int tz = tile & 15, ty = (tile >> 4) & 63, tx = tile >> 10;
        int dxl = lane >> 4, dyl = (lane >> 2) & 3, dzq = lane & 3;
        int vx = tx*4 + dxl, vy = ty*4 + dyl, vz0 = tz*16 + dzq*4;

        float cx = center[3*g+0], cy = center[3*g+1], cz = center[3*g+2];
        float r  = radius[g];
        float c00=cov_inv[9*g+0], c01=cov_inv[9*g+1], c02=cov_inv[9*g+2];
        float c10=cov_inv[9*g+3], c11=cov_inv[9*g+4], c12=cov_inv[9*g+5];
        float c20=cov_inv[9*g+6], c21=cov_inv[9*g+7], c22=cov_inv[9*g+8];
        float dr = dens_r[g], di = dens_i[g];

        int bx=(int)floorf(cx), by=(int)floorf(cy), bz=(int)floorf(cz);
        int xlo = max(max((int)floorf(cx - r), bx - RMAX), 0);
        int xhi = min(min((int)ceilf (cx + r), bx + RMAX), DD - 1);
        int ylo = max(max((int)floorf(cy - r), by - RMAX), 0);
        int yhi = min(min((int)ceilf (cy + r), by + RMAX), HH - 1);
        int zlo = max(max((int)floorf(cz - r), bz - RMAX), 0);
        int zhi = min(min((int)ceilf (cz + r), bz + RMAX), WW - 1);

        if (vx < xlo || vx > xhi || vy < ylo || vy > yhi) continue;
        float fx = ((float)vx - cx) * ihx;
        float fy = ((float)vy - cy) * ihy;
        for (int k = 0; k < 4; ++k) {
            int vz = vz0 + k;
            float fz = ((float)vz - cz) * ihz;
            float md = fx*(c00*fx + c01*fy + c02*fz)
                     + fy*(c10*fx + c11*fy + c12*fz)
                     + fz*(c20*fx + c21*fy + c22*fz);
            if (vz >= zlo && vz <= zhi && md <= 9.0f) {
                float wgt = __expf(-0.5f * md);
                size_t flat = ((size_t)vx * HH + vy) * WW + vz;
                atomicAdd(&vol_r[flat], wgt * dr);
                atomicAdd(&vol_i[flat], wgt * di);
            }
        }
    }
}

// ---------------- fallback scatter (only if ws too small) ----------------
__global__ __launch_bounds__(256) void splat_kernel(
    const float* __restrict__ center, const float* __restrict__ cov_inv,
    const float* __restrict__ dens_r, const float* __restrict__ dens_i,
    const float* __restrict__ radius, const float* __restrict__ half_shape,
    float* __restrict__ vol_r, float* __restrict__ vol_i, int N)
{
    int g = blockIdx.x;
    if (g >= N) return;
    float cx = center[3*g+0], cy = center[3*g+1], cz = center[3*g+2];
    float r  = radius[g];
    float c00 = cov_inv[9*g+0], c01 = cov_inv[9*g+1], c02 = cov_inv[9*g+2];
    float c10 = cov_inv[9*g+3], c11 = cov_inv[9*g+4], c12 = cov_inv[9*g+5];
    float c20 = cov_inv[9*g+6], c21 = cov_inv[9*g+7], c22 = cov_inv[9*g+8];
    float dr = dens_r[g], di = dens_i[g];
    float ihx = 1.0f/half_shape[0], ihy = 1.0f/half_shape[1], ihz = 1.0f/half_shape[2];
    int bx = (int)floorf(cx), by = (int)floorf(cy), bz = (int)floorf(cz);
    int xlo = max(max((int)floorf(cx - r), bx - RMAX), 0);
    int xhi = min(min((int)ceilf (cx + r), bx + RMAX), DD - 1);
    int ylo = max(max((int)floorf(cy - r), by - RMAX), 0);
    int yhi = min(min((int)ceilf (cy + r), by + RMAX), HH - 1);
    int zlo = max(max((int)floorf(cz - r), bz - RMAX), 0);
    int zhi = min(min((int)ceilf (cz + r), bz + RMAX), WW - 1);
    int nx = xhi-xlo+1, ny = yhi-ylo+1, nz = zhi-zlo+1;
    if (nx <= 0 || ny <= 0 || nz <= 0) return;
    int total = nx*ny*nz;
    for (int k = threadIdx.x; k < total; k += 256) {
        int iz = k % nz, tq = k / nz, iy = tq % ny, ix = tq / ny;
        int vx = xlo+ix, vy = ylo+iy, vz = zlo+iz;
        float dxn = ((float)vx - cx) * ihx;
        float dyn = ((float)vy - cy) * ihy;
        float dzn = ((float)vz - cz) * ihz;
        float md = dxn*(c00*dxn + c01*dyn + c02*dzn)
                 + dyn*(c10*dxn + c11*dyn + c12*dzn)
                 + dzn*(c20*dxn + c21*dyn + c22*dzn);
        if (md <= 9.0f) {
            float wgt = __expf(-0.5f*md);
            int flat = (vx*HH + vy)*WW + vz;
            atomicAdd(&vol_r[flat], wgt*dr);
            atomicAdd(&vol_i[flat], wgt*di);
        }
    }
}

extern "C" void kernel_launch(void* const* d_in, const int* in_sizes, int n_in,
                              void* d_out, int out_size, void* d_ws, size_t ws_size,
                              hipStream_t stream) {
    const float* center     = (const float*)d_in[0];
    const float* cov_inv    = (const float*)d_in[1];
    const float* dens_r     = (const float*)d_in[2];
    const float* dens_i     = (const float*)d_in[3];
    const float* radius     = (const float*)d_in[4];
    const float* half_shape = (const float*)d_in[5];
    int N = in_sizes[0] / 3;

    float* vol_r = (float*)d_out;
    float* vol_i = vol_r + (size_t)DD * HH * WW;

    // ws layout: [tile_recs | tile_cnt | ovf_cnt | ovf_list]
    size_t rec_floats = (size_t)NTILES * CAP * RECSZ;           // ~100.7 MB
    size_t need = rec_floats * sizeof(float)
                + ((size_t)NTILES + 4 + 2*OVF_CAP) * sizeof(int);
    if (ws_size < need) {
        (void)hipMemsetAsync(d_out, 0, (size_t)out_size * sizeof(float), stream);
        splat_kernel<<<N, 256, 0, stream>>>(center, cov_inv, dens_r, dens_i,
                                            radius, half_shape, vol_r, vol_i, N);
        return;
    }

    float* tile_recs = (float*)d_ws;
    int*   tile_cnt  = (int*)(tile_recs + rec_floats);   // NTILES
    int*   ovf_cnt   = tile_cnt + NTILES;                // 4
    int*   ovf_list  = ovf_cnt + 4;                      // 2*OVF_CAP

    (void)hipMemsetAsync(tile_cnt, 0, ((size_t)NTILES + 4) * sizeof(int), stream);
    // one wave per gaussian: 4 gaussians per 256-thread block
    fill_kernel<<<(N + 3)/4, 256, 0, stream>>>(center, cov_inv, dens_r, dens_i,
                                               radius, half_shape,
                                               tile_cnt, tile_recs,
                                               ovf_cnt, ovf_list, N);
    gather_kernel<<<NTILES/4, 256, 0, stream>>>(tile_cnt, tile_recs, half_shape,
                                                vol_r, vol_i);
    ovf_kernel<<<64, 64, 0, stream>>>(ovf_cnt, ovf_list, center, cov_inv,
                                      dens_r, dens_i, radius, half_shape,
                                      vol_r, vol_i);
}